// Round 1
// baseline (528.984 us; speedup 1.0000x reference)
//
#include <hip/hip_runtime.h>

typedef unsigned short u16;
typedef short short8 __attribute__((ext_vector_type(8)));
typedef float f32x4 __attribute__((ext_vector_type(4)));

// ---------- helpers ----------
__device__ __forceinline__ u16 f2b(float x){
  union{float f; unsigned u;} v; v.f = x;
  unsigned r = (v.u + 0x7FFFu + ((v.u >> 16) & 1u)) >> 16;
  return (u16)r;
}
__device__ __forceinline__ float b2f(u16 h){
  union{unsigned u; float f;} v; v.u = ((unsigned)h) << 16; return v.f;
}
__device__ __forceinline__ float sigm(float x){ return 1.0f/(1.0f + __expf(-x)); }
__device__ __forceinline__ float tanh_f(float x){ return 1.0f - 2.0f/(1.0f + __expf(2.0f*x)); }

// ---------- prep: xe gather->bf16, Wcomb, bias, Whh pair-split repack, W1 repack, hbt pad zero ----------
__global__ void prep_kernel(const int* __restrict__ x, const float* __restrict__ emb,
   const float* __restrict__ Wih_f, const float* __restrict__ Whh_f,
   const float* __restrict__ bih_f, const float* __restrict__ bhh_f,
   const float* __restrict__ Wih_b, const float* __restrict__ Whh_b,
   const float* __restrict__ bih_b, const float* __restrict__ bhh_b,
   const float* __restrict__ W1,
   u16* __restrict__ xe, u16* __restrict__ wc, float* __restrict__ biasC,
   float* __restrict__ whhP, u16* __restrict__ w1b, u16* __restrict__ hbt)
{
  int id = blockIdx.x*256 + threadIdx.x;
  const int N0 = 32768*128;   // xe  [p][k]
  const int N1 = 832*128;     // wc  [n][k]
  const int N2 = 800;         // biasC
  const int N3 = 80000;       // whhP [d][kk][p]  p=j*2+half, k=half*50+kk
  const int N4 = 672*320;     // w1b  (id = k*320+n)
  const int N5 = 32768*24;    // hbt pad cols 200..223
  if (id < N0){
    int p = id >> 7, k = id & 127;
    float v = 0.f;
    if (k < 100) v = emb[x[p]*100 + k];
    xe[id] = f2b(v);
    return;
  }
  id -= N0;
  if (id < N1){
    int n = id >> 7, k = id & 127;
    float v = 0.f;
    if (k < 100){
      if (n < 400) v = Wih_f[n*100+k];
      else if (n < 800) v = Wih_b[(n-400)*100+k];
    }
    wc[id] = f2b(v);
    return;
  }
  id -= N1;
  if (id < N2){
    biasC[id] = (id < 400) ? (bih_f[id]+bhh_f[id]) : (bih_b[id-400]+bhh_b[id-400]);
    return;
  }
  id -= N2;
  if (id < N3){
    int d = id / 40000; int rem = id - d*40000; int kk = rem / 800; int p = rem - kk*800;
    int j = p >> 1, half = p & 1;
    const float* W = d ? Whh_b : Whh_f;
    whhP[id] = W[j*100 + half*50 + kk];
    return;
  }
  id -= N3;
  if (id < N4){
    int k = id / 320; int n = id - k*320;
    int seg = k / 224; int wwk = k - seg*224;
    float v = 0.f;
    if (n < 300 && wwk < 200) v = W1[(seg*200 + wwk)*300 + n];
    w1b[n*672 + k] = f2b(v);
    return;
  }
  id -= N4;
  if (id < N5){
    int p = id / 24; int k = id - p*24;
    hbt[p*224 + 200 + k] = 0;
  }
}

// ---------- GEMM1: inp[d][b][t][j] = xe @ Wcomb^T + bias, bf16 MFMA ----------
// M=32768 (p=b*128+t), N=832 (pad of 800), K=128 (pad of 100)
__global__ __launch_bounds__(256) void gemm1_kernel(const u16* __restrict__ xe,
    const u16* __restrict__ wc, const float* __restrict__ biasC, u16* __restrict__ inp)
{
  __shared__ __align__(16) u16 As[64*136];   // stride 136: 2-way bank alias only
  __shared__ __align__(16) u16 Bs[64*136];
  const int m0 = blockIdx.x*64, n0 = blockIdx.y*64;
  const int tid = threadIdx.x;
  #pragma unroll
  for (int i=0;i<4;i++){
    int f = i*256 + tid;
    int row = f >> 4, c8 = f & 15;
    *(uint4*)&As[row*136 + c8*8] = *(const uint4*)&xe[(m0+row)*128 + c8*8];
    *(uint4*)&Bs[row*136 + c8*8] = *(const uint4*)&wc[(n0+row)*128 + c8*8];
  }
  __syncthreads();
  const int w = tid >> 6, lane = tid & 63, col = lane & 15, quad = lane >> 4;
  f32x4 acc[4];
  #pragma unroll
  for (int nt=0;nt<4;nt++) acc[nt] = (f32x4){0.f,0.f,0.f,0.f};
  #pragma unroll
  for (int kc=0;kc<4;kc++){
    short8 af = *(const short8*)&As[(w*16+col)*136 + kc*32 + quad*8];
    #pragma unroll
    for (int nt=0;nt<4;nt++){
      short8 bfrag = *(const short8*)&Bs[(nt*16+col)*136 + kc*32 + quad*8];
      acc[nt] = __builtin_amdgcn_mfma_f32_16x16x32_bf16(af, bfrag, acc[nt], 0, 0, 0);
    }
  }
  #pragma unroll
  for (int nt=0;nt<4;nt++){
    int n = n0 + nt*16 + col;
    if (n < 800){
      float bs = biasC[n];
      int dir = (n >= 400) ? 1 : 0;
      int j = n - dir*400;
      #pragma unroll
      for (int r=0;r<4;r++){
        int m = m0 + w*16 + quad*4 + r;
        inp[(dir*32768 + m)*400 + j] = f2b(acc[nt][r] + bs);
      }
    }
  }
}

// ---------- LSTM recurrence: 512 chains (dir,b), one block each ----------
// 800 compute threads: thread = (j, half); each holds whh[50] (no spill),
// pair-reduces the 100-k dot product with one shfl_xor.
// gates: i[0:100) f[100:200) g[200:300) o[300:400)
__global__ __launch_bounds__(832, 7) void lstm_kernel(const u16* __restrict__ inp,
    const float* __restrict__ whhP, u16* __restrict__ hbt)
{
  const int cid = blockIdx.x;
  const int b = cid & 255, dir = cid >> 8;
  const int tid = threadIdx.x;
  const int j = tid >> 1, half = tid & 1;
  __shared__ __align__(16) float hs[104];
  __shared__ float act[400];
  float whh[50];
  if (tid < 800){
    const float* wp = whhP + dir*40000 + tid;   // whhP[d][kk][p], coalesced over p
    #pragma unroll
    for (int k=0;k<50;k++) whh[k] = wp[k*800];
  }
  if (tid < 104) hs[tid] = 0.f;
  float c = 0.f;
  const u16* ipt = inp + (dir*32768 + b*128)*400 + (dir ? 127*400 : 0);
  u16* hpt = hbt + b*128*224 + (dir ? 127*224 : 0) + dir*100 + tid;
  const int dIp = dir ? -400 : 400;
  const int dHp = dir ? -224 : 224;
  __syncthreads();
  for (int step=0; step<128; step++){
    if (tid < 800){
      const float2* h2 = (const float2*)(hs + half*50);   // 8B aligned
      float a0=0.f,a1=0.f,a2=0.f,a3=0.f;
      #pragma unroll
      for (int kk=0;kk<12;kk++){
        float2 u = h2[2*kk], v = h2[2*kk+1];
        a0 = fmaf(whh[4*kk+0], u.x, a0);
        a1 = fmaf(whh[4*kk+1], u.y, a1);
        a2 = fmaf(whh[4*kk+2], v.x, a2);
        a3 = fmaf(whh[4*kk+3], v.y, a3);
      }
      { float2 u = h2[24];
        a0 = fmaf(whh[48], u.x, a0);
        a1 = fmaf(whh[49], u.y, a1); }
      float part = (a0+a2)+(a1+a3);
      part += __shfl_xor(part, 1, 64);
      if (half == 0){
        float xg = b2f(ipt[j]) + part;
        act[j] = (j >= 200 && j < 300) ? tanh_f(xg) : sigm(xg);
      }
    }
    __syncthreads();
    if (tid < 100){
      float ig = act[tid], fg = act[100+tid], gg = act[200+tid], og = act[300+tid];
      c = fg*c + ig*gg;
      float hk = og * tanh_f(c);
      hs[tid] = hk;
      *hpt = f2b(hk);
      hpt += dHp;
    }
    ipt += dIp;
    __syncthreads();
  }
}

// ---------- MLP: gathered bf16 MFMA GEMM + tanh + W2 + softmax fused ----------
// M=65280 (m=b*255+c), N=320 (pad of 300), K=672 (3 segments of 224, valid 200)
__global__ __launch_bounds__(512) void mlp_kernel(const u16* __restrict__ hbt,
    const u16* __restrict__ w1b, const int* __restrict__ paths,
    const float* __restrict__ b1, const float* __restrict__ W2,
    const float* __restrict__ b2, float* __restrict__ out)
{
  __shared__ __align__(16) u16 As[128*40];   // stride 40: 2-way alias only
  __shared__ __align__(16) u16 Bs[320*40];
  const int m0 = blockIdx.x*128;
  const int tid = threadIdx.x;
  const int arow = tid >> 2, ac8 = tid & 3;
  const int am = m0 + arow;
  const int ab = am / 255;   // batch index of this A row
  const int w = tid >> 6, lane = tid & 63, col = lane & 15, quad = lane >> 4;
  f32x4 acc[20];
  #pragma unroll
  for (int nt=0;nt<20;nt++) acc[nt] = (f32x4){0.f,0.f,0.f,0.f};
  for (int kc=0;kc<21;kc++){
    __syncthreads();
    // stage W1 chunk: 320 rows x 32 k
    for (int f = tid; f < 1280; f += 512){
      int br = f >> 2, bc = f & 3;
      *(uint4*)&Bs[br*40 + bc*8] = *(const uint4*)&w1b[br*672 + kc*32 + bc*8];
    }
    // stage gathered A chunk: 128 rows x 32 k (one 16B piece per thread)
    int seg = (kc >= 14) ? 2 : (kc >= 7 ? 1 : 0);
    int ko = kc - seg*7;
    int it = paths[am*3 + seg];
    uint4 v = make_uint4(0u,0u,0u,0u);
    if (it >= 0){
      int t = it > 127 ? 127 : it;
      v = *(const uint4*)&hbt[(ab*128 + t)*224 + ko*32 + ac8*8];
    }
    *(uint4*)&As[arow*40 + ac8*8] = v;
    __syncthreads();
    short8 af = *(const short8*)&As[(w*16+col)*40 + quad*8];
    #pragma unroll
    for (int nt=0;nt<20;nt++){
      short8 bfrag = *(const short8*)&Bs[(nt*16+col)*40 + quad*8];
      acc[nt] = __builtin_amdgcn_mfma_f32_16x16x32_bf16(af, bfrag, acc[nt], 0, 0, 0);
    }
  }
  // epilogue: hdn = tanh(z1+b1); z2 = hdn@W2+b2; softmax; store
  float pz[4][3];
  #pragma unroll
  for (int r=0;r<4;r++){ pz[r][0]=0.f; pz[r][1]=0.f; pz[r][2]=0.f; }
  #pragma unroll
  for (int nt=0;nt<20;nt++){
    int n = nt*16 + col;
    if (n < 300){
      float bb = b1[n];
      float w20 = W2[n*3+0], w21 = W2[n*3+1], w22 = W2[n*3+2];
      #pragma unroll
      for (int r=0;r<4;r++){
        float hdn = tanh_f(acc[nt][r] + bb);
        pz[r][0] = fmaf(hdn, w20, pz[r][0]);
        pz[r][1] = fmaf(hdn, w21, pz[r][1]);
        pz[r][2] = fmaf(hdn, w22, pz[r][2]);
      }
    }
  }
  #pragma unroll
  for (int off=1; off<16; off<<=1){
    #pragma unroll
    for (int r=0;r<4;r++){
      pz[r][0] += __shfl_xor(pz[r][0], off, 64);
      pz[r][1] += __shfl_xor(pz[r][1], off, 64);
      pz[r][2] += __shfl_xor(pz[r][2], off, 64);
    }
  }
  float c0 = b2[0], c1 = b2[1], c2 = b2[2];
  #pragma unroll
  for (int r=0;r<4;r++){
    float z0 = pz[r][0]+c0, z1 = pz[r][1]+c1, z2 = pz[r][2]+c2;
    float mx = fmaxf(z0, fmaxf(z1, z2));
    float e0 = __expf(z0-mx), e1 = __expf(z1-mx), e2 = __expf(z2-mx);
    float inv = 1.0f/(e0+e1+e2);
    if (col < 3){
      float pv = (col==0 ? e0 : (col==1 ? e1 : e2)) * inv;
      out[(m0 + w*16 + quad*4 + r)*3 + col] = pv;
    }
  }
}

// ---------- launch ----------
extern "C" void kernel_launch(void* const* d_in, const int* in_sizes, int n_in,
                              void* d_out, int out_size, void* d_ws, size_t ws_size,
                              hipStream_t stream)
{
  const int*   x     = (const int*)  d_in[0];
  const int*   paths = (const int*)  d_in[1];
  const float* emb   = (const float*)d_in[2];
  const float* Wih_f = (const float*)d_in[3];
  const float* Whh_f = (const float*)d_in[4];
  const float* bih_f = (const float*)d_in[5];
  const float* bhh_f = (const float*)d_in[6];
  const float* Wih_b = (const float*)d_in[7];
  const float* Whh_b = (const float*)d_in[8];
  const float* bih_b = (const float*)d_in[9];
  const float* bhh_b = (const float*)d_in[10];
  const float* W1    = (const float*)d_in[11];
  const float* b1    = (const float*)d_in[12];
  const float* W2    = (const float*)d_in[13];
  const float* b2    = (const float*)d_in[14];
  float* out = (float*)d_out;

  char* ws = (char*)d_ws;
  u16*   xe    = (u16*)  (ws + 0);          //  8,388,608 B
  u16*   wc    = (u16*)  (ws + 8388608);    //    212,992 B
  float* biasC = (float*)(ws + 8601600);    //      3,200 B
  float* whhP  = (float*)(ws + 8604800);    //    320,000 B
  u16*   w1b   = (u16*)  (ws + 8924800);    //    430,080 B
  u16*   inp   = (u16*)  (ws + 9354880);    // 52,428,800 B
  u16*   hbt   = (u16*)  (ws + 61783680);   // 14,680,064 B  (total 76,463,744)

  const int prep_total = 32768*128 + 832*128 + 800 + 80000 + 672*320 + 32768*24;
  prep_kernel<<<(prep_total + 255)/256, 256, 0, stream>>>(
      x, emb, Wih_f, Whh_f, bih_f, bhh_f, Wih_b, Whh_b, bih_b, bhh_b, W1,
      xe, wc, biasC, whhP, w1b, hbt);
  gemm1_kernel<<<dim3(512, 13), 256, 0, stream>>>(xe, wc, biasC, inp);
  lstm_kernel<<<512, 832, 0, stream>>>(inp, whhP, hbt);
  mlp_kernel<<<510, 512, 0, stream>>>(hbt, w1b, paths, b1, W2, b2, out);
}

// Round 2
// 348.020 us; speedup vs baseline: 1.5200x; 1.5200x over previous
//
#include <hip/hip_runtime.h>

typedef unsigned short u16;
typedef short short8 __attribute__((ext_vector_type(8)));
typedef float f32x4 __attribute__((ext_vector_type(4)));

// ---------- helpers ----------
__device__ __forceinline__ u16 f2b(float x){
  union{float f; unsigned u;} v; v.f = x;
  unsigned r = (v.u + 0x7FFFu + ((v.u >> 16) & 1u)) >> 16;
  return (u16)r;
}
__device__ __forceinline__ float b2f(u16 h){
  union{unsigned u; float f;} v; v.u = ((unsigned)h) << 16; return v.f;
}
__device__ __forceinline__ float sigm(float x){ return 1.0f/(1.0f + __expf(-x)); }
__device__ __forceinline__ float tanh_f(float x){ return 1.0f - 2.0f/(1.0f + __expf(2.0f*x)); }

// ---------- prep: xe gather->bf16, Wcomb, bias, Whh^T, W1 repack, hbt pad zero ----------
__global__ void prep_kernel(const int* __restrict__ x, const float* __restrict__ emb,
   const float* __restrict__ Wih_f, const float* __restrict__ Whh_f,
   const float* __restrict__ bih_f, const float* __restrict__ bhh_f,
   const float* __restrict__ Wih_b, const float* __restrict__ Whh_b,
   const float* __restrict__ bih_b, const float* __restrict__ bhh_b,
   const float* __restrict__ W1,
   u16* __restrict__ xe, u16* __restrict__ wc, float* __restrict__ biasC,
   float* __restrict__ whhT, u16* __restrict__ w1b, u16* __restrict__ hbt)
{
  int id = blockIdx.x*256 + threadIdx.x;
  const int N0 = 32768*128;   // xe  [p][k]
  const int N1 = 832*128;     // wc  [n][k]
  const int N2 = 800;         // biasC
  const int N3 = 80000;       // whhT [d][k][j]
  const int N4 = 672*320;     // w1b  (id = k*320+n)
  const int N5 = 32768*24;    // hbt pad cols 200..223
  if (id < N0){
    int p = id >> 7, k = id & 127;
    float v = 0.f;
    if (k < 100) v = emb[x[p]*100 + k];
    xe[id] = f2b(v);
    return;
  }
  id -= N0;
  if (id < N1){
    int n = id >> 7, k = id & 127;
    float v = 0.f;
    if (k < 100){
      if (n < 400) v = Wih_f[n*100+k];
      else if (n < 800) v = Wih_b[(n-400)*100+k];
    }
    wc[id] = f2b(v);
    return;
  }
  id -= N1;
  if (id < N2){
    biasC[id] = (id < 400) ? (bih_f[id]+bhh_f[id]) : (bih_b[id-400]+bhh_b[id-400]);
    return;
  }
  id -= N2;
  if (id < N3){
    int d = id / 40000; int rem = id - d*40000; int k = rem / 400; int j = rem - k*400;
    const float* W = d ? Whh_b : Whh_f;
    whhT[id] = W[j*100 + k];
    return;
  }
  id -= N3;
  if (id < N4){
    int k = id / 320; int n = id - k*320;
    int seg = k / 224; int wwk = k - seg*224;
    float v = 0.f;
    if (n < 300 && wwk < 200) v = W1[(seg*200 + wwk)*300 + n];
    w1b[n*672 + k] = f2b(v);
    return;
  }
  id -= N4;
  if (id < N5){
    int p = id / 24; int k = id - p*24;
    hbt[p*224 + 200 + k] = 0;
  }
}

// ---------- GEMM1: inp[d][b][t][j] = xe @ Wcomb^T + bias, bf16 MFMA ----------
// M=32768 (p=b*128+t), N=832 (pad of 800), K=128 (pad of 100)
__global__ __launch_bounds__(256) void gemm1_kernel(const u16* __restrict__ xe,
    const u16* __restrict__ wc, const float* __restrict__ biasC, u16* __restrict__ inp)
{
  __shared__ __align__(16) u16 As[64*136];   // stride 136: 2-way bank alias only
  __shared__ __align__(16) u16 Bs[64*136];
  const int m0 = blockIdx.x*64, n0 = blockIdx.y*64;
  const int tid = threadIdx.x;
  #pragma unroll
  for (int i=0;i<4;i++){
    int f = i*256 + tid;
    int row = f >> 4, c8 = f & 15;
    *(uint4*)&As[row*136 + c8*8] = *(const uint4*)&xe[(m0+row)*128 + c8*8];
    *(uint4*)&Bs[row*136 + c8*8] = *(const uint4*)&wc[(n0+row)*128 + c8*8];
  }
  __syncthreads();
  const int w = tid >> 6, lane = tid & 63, col = lane & 15, quad = lane >> 4;
  f32x4 acc[4];
  #pragma unroll
  for (int nt=0;nt<4;nt++) acc[nt] = (f32x4){0.f,0.f,0.f,0.f};
  #pragma unroll
  for (int kc=0;kc<4;kc++){
    short8 af = *(const short8*)&As[(w*16+col)*136 + kc*32 + quad*8];
    #pragma unroll
    for (int nt=0;nt<4;nt++){
      short8 bfrag = *(const short8*)&Bs[(nt*16+col)*136 + kc*32 + quad*8];
      acc[nt] = __builtin_amdgcn_mfma_f32_16x16x32_bf16(af, bfrag, acc[nt], 0, 0, 0);
    }
  }
  #pragma unroll
  for (int nt=0;nt<4;nt++){
    int n = n0 + nt*16 + col;
    if (n < 800){
      float bs = biasC[n];
      int dir = (n >= 400) ? 1 : 0;
      int j = n - dir*400;
      #pragma unroll
      for (int r=0;r<4;r++){
        int m = m0 + w*16 + quad*4 + r;
        inp[(dir*32768 + m)*400 + j] = f2b(acc[nt][r] + bs);
      }
    }
  }
}

// ---------- LSTM recurrence: 512 chains (dir,b), one block each ----------
// thread j computes gate j (j<400); whh[100] held in VGPRs (budget 256 via
// __launch_bounds__(448,2) -- (448,4)'s 128-reg budget forced AGPR copies,
// (832,7)'s 72-reg budget forced scratch spill; both measured slower).
// gates: i[0:100) f[100:200) g[200:300) o[300:400)
__global__ __launch_bounds__(448, 2) void lstm_kernel(const u16* __restrict__ inp,
    const float* __restrict__ whhT, u16* __restrict__ hbt)
{
  const int cid = blockIdx.x;
  const int b = cid & 255, dir = cid >> 8;
  const int jj = threadIdx.x;
  __shared__ __align__(16) float hs[104];
  __shared__ float act[400];
  float whh[100];
  if (jj < 400){
    const float* wp = whhT + dir*40000 + jj;   // whhT[d][k][j], coalesced over j
    #pragma unroll
    for (int k=0;k<100;k++) whh[k] = wp[k*400];
  }
  if (jj < 104) hs[jj] = 0.f;
  float c = 0.f;
  const u16* ipt = inp + (dir*32768 + b*128)*400 + (dir ? 127*400 : 0);
  u16* hpt = hbt + b*128*224 + (dir ? 127*224 : 0) + dir*100 + jj;
  const int dIp = dir ? -400 : 400;
  const int dHp = dir ? -224 : 224;
  // 1-deep pipeline on the gate-preactivation load
  u16 curraw = (jj < 400) ? ipt[jj] : (u16)0;
  __syncthreads();
  for (int step=0; step<128; step++){
    if (jj < 400){
      float pre = b2f(curraw);
      // issue next step's load now; it drains under the FMA loop + barriers
      if (step < 127) curraw = ipt[dIp + jj];
      ipt += dIp;
      const float4* h4 = (const float4*)hs;
      float a0=0.f,a1=0.f,a2=0.f,a3=0.f;
      #pragma unroll
      for (int kk=0;kk<25;kk++){
        float4 hv = h4[kk];
        a0 = fmaf(whh[4*kk+0], hv.x, a0);
        a1 = fmaf(whh[4*kk+1], hv.y, a1);
        a2 = fmaf(whh[4*kk+2], hv.z, a2);
        a3 = fmaf(whh[4*kk+3], hv.w, a3);
      }
      float xg = pre + ((a0+a1)+(a2+a3));
      act[jj] = (jj >= 200 && jj < 300) ? tanh_f(xg) : sigm(xg);
    }
    __syncthreads();
    if (jj < 100){
      float ig = act[jj], fg = act[100+jj], gg = act[200+jj], og = act[300+jj];
      c = fg*c + ig*gg;
      float hk = og * tanh_f(c);
      hs[jj] = hk;
      *hpt = f2b(hk);
      hpt += dHp;
    }
    __syncthreads();
  }
}

// ---------- MLP: gathered bf16 MFMA GEMM + tanh + W2 + softmax fused ----------
// M=65280 (m=b*255+c), N=320 (pad of 300), K=672 (3 segments of 224, valid 200)
__global__ __launch_bounds__(512) void mlp_kernel(const u16* __restrict__ hbt,
    const u16* __restrict__ w1b, const int* __restrict__ paths,
    const float* __restrict__ b1, const float* __restrict__ W2,
    const float* __restrict__ b2, float* __restrict__ out)
{
  __shared__ __align__(16) u16 As[128*40];   // stride 40: 2-way alias only
  __shared__ __align__(16) u16 Bs[320*40];
  const int m0 = blockIdx.x*128;
  const int tid = threadIdx.x;
  const int arow = tid >> 2, ac8 = tid & 3;
  const int am = m0 + arow;
  const int ab = am / 255;   // batch index of this A row
  const int w = tid >> 6, lane = tid & 63, col = lane & 15, quad = lane >> 4;
  f32x4 acc[20];
  #pragma unroll
  for (int nt=0;nt<20;nt++) acc[nt] = (f32x4){0.f,0.f,0.f,0.f};
  for (int kc=0;kc<21;kc++){
    __syncthreads();
    // stage W1 chunk: 320 rows x 32 k
    for (int f = tid; f < 1280; f += 512){
      int br = f >> 2, bc = f & 3;
      *(uint4*)&Bs[br*40 + bc*8] = *(const uint4*)&w1b[br*672 + kc*32 + bc*8];
    }
    // stage gathered A chunk: 128 rows x 32 k (one 16B piece per thread)
    int seg = (kc >= 14) ? 2 : (kc >= 7 ? 1 : 0);
    int ko = kc - seg*7;
    int it = paths[am*3 + seg];
    uint4 v = make_uint4(0u,0u,0u,0u);
    if (it >= 0){
      int t = it > 127 ? 127 : it;
      v = *(const uint4*)&hbt[(ab*128 + t)*224 + ko*32 + ac8*8];
    }
    *(uint4*)&As[arow*40 + ac8*8] = v;
    __syncthreads();
    short8 af = *(const short8*)&As[(w*16+col)*40 + quad*8];
    #pragma unroll
    for (int nt=0;nt<20;nt++){
      short8 bfrag = *(const short8*)&Bs[(nt*16+col)*40 + quad*8];
      acc[nt] = __builtin_amdgcn_mfma_f32_16x16x32_bf16(af, bfrag, acc[nt], 0, 0, 0);
    }
  }
  // epilogue: hdn = tanh(z1+b1); z2 = hdn@W2+b2; softmax; store
  float pz[4][3];
  #pragma unroll
  for (int r=0;r<4;r++){ pz[r][0]=0.f; pz[r][1]=0.f; pz[r][2]=0.f; }
  #pragma unroll
  for (int nt=0;nt<20;nt++){
    int n = nt*16 + col;
    if (n < 300){
      float bb = b1[n];
      float w20 = W2[n*3+0], w21 = W2[n*3+1], w22 = W2[n*3+2];
      #pragma unroll
      for (int r=0;r<4;r++){
        float hdn = tanh_f(acc[nt][r] + bb);
        pz[r][0] = fmaf(hdn, w20, pz[r][0]);
        pz[r][1] = fmaf(hdn, w21, pz[r][1]);
        pz[r][2] = fmaf(hdn, w22, pz[r][2]);
      }
    }
  }
  #pragma unroll
  for (int off=1; off<16; off<<=1){
    #pragma unroll
    for (int r=0;r<4;r++){
      pz[r][0] += __shfl_xor(pz[r][0], off, 64);
      pz[r][1] += __shfl_xor(pz[r][1], off, 64);
      pz[r][2] += __shfl_xor(pz[r][2], off, 64);
    }
  }
  float c0 = b2[0], c1 = b2[1], c2 = b2[2];
  #pragma unroll
  for (int r=0;r<4;r++){
    float z0 = pz[r][0]+c0, z1 = pz[r][1]+c1, z2 = pz[r][2]+c2;
    float mx = fmaxf(z0, fmaxf(z1, z2));
    float e0 = __expf(z0-mx), e1 = __expf(z1-mx), e2 = __expf(z2-mx);
    float inv = 1.0f/(e0+e1+e2);
    if (col < 3){
      float pv = (col==0 ? e0 : (col==1 ? e1 : e2)) * inv;
      out[(m0 + w*16 + quad*4 + r)*3 + col] = pv;
    }
  }
}

// ---------- launch ----------
extern "C" void kernel_launch(void* const* d_in, const int* in_sizes, int n_in,
                              void* d_out, int out_size, void* d_ws, size_t ws_size,
                              hipStream_t stream)
{
  const int*   x     = (const int*)  d_in[0];
  const int*   paths = (const int*)  d_in[1];
  const float* emb   = (const float*)d_in[2];
  const float* Wih_f = (const float*)d_in[3];
  const float* Whh_f = (const float*)d_in[4];
  const float* bih_f = (const float*)d_in[5];
  const float* bhh_f = (const float*)d_in[6];
  const float* Wih_b = (const float*)d_in[7];
  const float* Whh_b = (const float*)d_in[8];
  const float* bih_b = (const float*)d_in[9];
  const float* bhh_b = (const float*)d_in[10];
  const float* W1    = (const float*)d_in[11];
  const float* b1    = (const float*)d_in[12];
  const float* W2    = (const float*)d_in[13];
  const float* b2    = (const float*)d_in[14];
  float* out = (float*)d_out;

  char* ws = (char*)d_ws;
  u16*   xe    = (u16*)  (ws + 0);          //  8,388,608 B
  u16*   wc    = (u16*)  (ws + 8388608);    //    212,992 B
  float* biasC = (float*)(ws + 8601600);    //      3,200 B
  float* whhT  = (float*)(ws + 8604800);    //    320,000 B
  u16*   w1b   = (u16*)  (ws + 8924800);    //    430,080 B
  u16*   inp   = (u16*)  (ws + 9354880);    // 52,428,800 B
  u16*   hbt   = (u16*)  (ws + 61783680);   // 14,680,064 B  (total 76,463,744)

  const int prep_total = 32768*128 + 832*128 + 800 + 80000 + 672*320 + 32768*24;
  prep_kernel<<<(prep_total + 255)/256, 256, 0, stream>>>(
      x, emb, Wih_f, Whh_f, bih_f, bhh_f, Wih_b, Whh_b, bih_b, bhh_b, W1,
      xe, wc, biasC, whhT, w1b, hbt);
  gemm1_kernel<<<dim3(512, 13), 256, 0, stream>>>(xe, wc, biasC, inp);
  lstm_kernel<<<512, 448, 0, stream>>>(inp, whhT, hbt);
  mlp_kernel<<<510, 512, 0, stream>>>(hbt, w1b, paths, b1, W2, b2, out);
}